// Round 3
// baseline (150.815 us; speedup 1.0000x reference)
//
#include <hip/hip_runtime.h>
#include <math.h>

#define RES 128
#define NS 64
#define EPSF 1e-8f

// General 4x4 inverse, Gauss-Jordan with partial pivoting, double internal.
__device__ void inv4x4(const float* __restrict__ A, double out[4][4]) {
    double m[4][8];
    for (int r = 0; r < 4; ++r) {
        for (int c = 0; c < 4; ++c) {
            m[r][c]     = (double)A[r * 4 + c];
            m[r][c + 4] = (r == c) ? 1.0 : 0.0;
        }
    }
    for (int col = 0; col < 4; ++col) {
        int piv = col;
        double best = fabs(m[col][col]);
        for (int r = col + 1; r < 4; ++r) {
            double v = fabs(m[r][col]);
            if (v > best) { best = v; piv = r; }
        }
        if (piv != col) {
            for (int c = 0; c < 8; ++c) {
                double t = m[col][c]; m[col][c] = m[piv][c]; m[piv][c] = t;
            }
        }
        double inv = 1.0 / m[col][col];
        for (int c = 0; c < 8; ++c) m[col][c] *= inv;
        for (int r = 0; r < 4; ++r) {
            if (r == col) continue;
            double f = m[r][col];
            for (int c = 0; c < 8; ++c) m[r][c] -= f * m[col][c];
        }
    }
    for (int r = 0; r < 4; ++r)
        for (int c = 0; c < 4; ++c)
            out[r][c] = m[r][c + 4];
}

// Zero-padding corner fetch; NaN-safe (NaN coords fail the >= tests -> 0,
// matching jnp.where(valid, v*w, 0) since NaN comparisons are false).
__device__ __forceinline__ float cornerf(const float* __restrict__ vol,
                                         float xf, float yf, float zf, float w) {
    if (xf >= 0.f && xf <= 127.f &&
        yf >= 0.f && yf <= 127.f &&
        zf >= 0.f && zf <= 127.f) {
        int xi = (int)xf, yi = (int)yf, zi = (int)zf;
        return vol[(zi * RES + yi) * RES + xi] * w;
    }
    return 0.f;
}

__global__ __launch_bounds__(256) void dsv_render(
    const float* __restrict__ vol,
    const float* __restrict__ wvt,
    const float* __restrict__ proj,
    const float* __restrict__ cam,
    const float* __restrict__ bbox,
    const int*   __restrict__ pH,
    const int*   __restrict__ pW,
    const int*   __restrict__ pmode,
    float*       __restrict__ out)
{
    __shared__ float sC[28];

    const int H = pH[0];
    const int W = pW[0];
    const int mode = pmode[0];

    if (threadIdx.x == 0) {
        double vi[4][4], pinv[4][4];
        inv4x4(wvt, vi);
        inv4x4(proj, pinv);
        // M = proj_inv @ view_inv  (row-vector convention: wp = ndc @ M)
        for (int i = 0; i < 4; ++i) {
            for (int j = 0; j < 4; ++j) {
                double s = 0.0;
                for (int k = 0; k < 4; ++k) s += pinv[i][k] * vi[k][j];
                sC[i * 4 + j] = (float)s;
            }
        }
        // mode-0 (orthographic) constants
        float bminx = bbox[0], bminy = bbox[1], bminz = bbox[2];
        float bmaxx = bbox[3], bmaxy = bbox[4], bmaxz = bbox[5];
        float ex = bmaxx - bminx, ey = bmaxy - bminy, ez = bmaxz - bminz;
        float ddx = -(float)vi[2][0], ddy = -(float)vi[2][1], ddz = -(float)vi[2][2];
        float nn = sqrtf(ddx * ddx + ddy * ddy + ddz * ddz) + EPSF;
        ddx /= nn; ddy /= nn; ddz /= nn;
        float diag = sqrtf(ex * ex + ey * ey + ez * ez);
        sC[16] = ddx; sC[17] = ddy; sC[18] = ddz;
        sC[19] = (float)vi[0][0] * ex * 0.5f;
        sC[20] = (float)vi[0][1] * ex * 0.5f;
        sC[21] = (float)vi[0][2] * ex * 0.5f;
        sC[22] = (float)vi[1][0] * ey * 0.5f;
        sC[23] = (float)vi[1][1] * ey * 0.5f;
        sC[24] = (float)vi[1][2] * ey * 0.5f;
        sC[25] = (bminx + bmaxx) * 0.5f - ddx * diag * 0.5f;
        sC[26] = (bminy + bmaxy) * 0.5f - ddy * diag * 0.5f;
        sC[27] = (bminz + bmaxz) * 0.5f - ddz * diag * 0.5f;
    }
    __syncthreads();

    const float bminx = bbox[0], bminy = bbox[1], bminz = bbox[2];
    const float bmaxx = bbox[3], bmaxy = bbox[4], bmaxz = bbox[5];
    // coords = (pts_norm+1)*0.5*(R-1) collapses to (p - bmin) * (R-1)/extent
    const float kx = 127.0f / (bmaxx - bminx + EPSF);
    const float ky = 127.0f / (bmaxy - bminy + EPSF);
    const float kz = 127.0f / (bmaxz - bminz + EPSF);
    const float camx = cam[0], camy = cam[1], camz = cam[2];

    const int nTx = (W + 15) >> 4;
    const int nTy = (H + 15) >> 4;
    const int nTiles = nTx * nTy;

    for (int tile = blockIdx.x; tile < nTiles; tile += gridDim.x) {
        const int ti = tile / nTx;
        const int tj = tile - ti * nTx;
        const int i = ti * 16 + ((int)threadIdx.x >> 4);
        const int j = tj * 16 + ((int)threadIdx.x & 15);
        if (i >= H || j >= W) continue;

        const float nx = (float)j / (float)(W - 1) * 2.0f - 1.0f;
        const float ny = (float)i / (float)(H - 1) * 2.0f - 1.0f;

        float ox, oy, oz, dx, dy, dz;
        if (mode == 0) {
            dx = sC[16]; dy = sC[17]; dz = sC[18];
            ox = sC[25] + nx * sC[19] + ny * sC[22];
            oy = sC[26] + nx * sC[20] + ny * sC[23];
            oz = sC[27] + nx * sC[21] + ny * sC[24];
        } else {
            float wx = nx * sC[0] + ny * sC[4] + sC[8]  + sC[12];
            float wy = nx * sC[1] + ny * sC[5] + sC[9]  + sC[13];
            float wz = nx * sC[2] + ny * sC[6] + sC[10] + sC[14];
            float ww = nx * sC[3] + ny * sC[7] + sC[11] + sC[15];
            float invw = 1.0f / (ww + EPSF);
            wx *= invw; wy *= invw; wz *= invw;
            ox = camx; oy = camy; oz = camz;
            dx = wx - ox; dy = wy - oy; dz = wz - oz;
            float n = sqrtf(dx * dx + dy * dy + dz * dz) + EPSF;
            dx /= n; dy /= n; dz /= n;
        }

        // AABB slab test (with reference's +EPS on dir)
        const float ix = 1.0f / (dx + EPSF);
        const float iy = 1.0f / (dy + EPSF);
        const float iz = 1.0f / (dz + EPSF);
        float t1 = (bminx - ox) * ix, t2 = (bmaxx - ox) * ix;
        float tn = fminf(t1, t2), tf = fmaxf(t1, t2);
        t1 = (bminy - oy) * iy; t2 = (bmaxy - oy) * iy;
        tn = fmaxf(tn, fminf(t1, t2)); tf = fminf(tf, fmaxf(t1, t2));
        t1 = (bminz - oz) * iz; t2 = (bmaxz - oz) * iz;
        tn = fmaxf(tn, fminf(t1, t2)); tf = fminf(tf, fmaxf(t1, t2));
        tn = fmaxf(tn, 0.0f);
        const bool valid = tf > tn;
        const float range = tf - tn;

        // Per-ray affine into voxel space: c(s) = base + step * s, s = 0..63
        const float sdx = dx * kx, sdy = dy * ky, sdz = dz * kz;       // d(coord)/dt
        const float basex = fmaf(sdx, tn, (ox - bminx) * kx);
        const float basey = fmaf(sdy, tn, (oy - bminy) * ky);
        const float basez = fmaf(sdz, tn, (oz - bminz) * kz);
        const float r63 = range * (1.0f / 63.0f);
        const float qx = sdx * r63, qy = sdy * r63, qz = sdz * r63;    // d(coord)/ds

        float sum = 0.0f;
        #pragma unroll 4
        for (int s = 0; s < NS; ++s) {
            const float fs = (float)s;
            const float cx = fmaf(qx, fs, basex);
            const float cy = fmaf(qy, fs, basey);
            const float cz = fmaf(qz, fs, basez);
            const float x0 = floorf(cx), y0 = floorf(cy), z0 = floorf(cz);
            const float fx = cx - x0, fy = cy - y0, fz = cz - z0;
            const float gx = 1.0f - fx, gy = 1.0f - fy, gz = 1.0f - fz;

            if (x0 >= 0.f && x0 <= 126.f &&
                y0 >= 0.f && y0 <= 126.f &&
                z0 >= 0.f && z0 <= 126.f) {
                const int base = (((int)z0) * RES + ((int)y0)) * RES + ((int)x0);
                const float v000 = vol[base];
                const float v100 = vol[base + 1];
                const float v010 = vol[base + RES];
                const float v110 = vol[base + RES + 1];
                const float v001 = vol[base + RES * RES];
                const float v101 = vol[base + RES * RES + 1];
                const float v011 = vol[base + RES * RES + RES];
                const float v111 = vol[base + RES * RES + RES + 1];
                const float gygz = gy * gz, fygz = fy * gz;
                const float gyfz = gy * fz, fyfz = fy * fz;
                sum += v000 * (gx * gygz) + v100 * (fx * gygz)
                     + v010 * (gx * fygz) + v110 * (fx * fygz)
                     + v001 * (gx * gyfz) + v101 * (fx * gyfz)
                     + v011 * (gx * fyfz) + v111 * (fx * fyfz);
            } else {
                sum += cornerf(vol, x0,       y0,       z0,       gx * gy * gz);
                sum += cornerf(vol, x0 + 1.f, y0,       z0,       fx * gy * gz);
                sum += cornerf(vol, x0,       y0 + 1.f, z0,       gx * fy * gz);
                sum += cornerf(vol, x0 + 1.f, y0 + 1.f, z0,       fx * fy * gz);
                sum += cornerf(vol, x0,       y0,       z0 + 1.f, gx * gy * fz);
                sum += cornerf(vol, x0 + 1.f, y0,       z0 + 1.f, fx * gy * fz);
                sum += cornerf(vol, x0,       y0 + 1.f, z0 + 1.f, gx * fy * fz);
                sum += cornerf(vol, x0 + 1.f, y0 + 1.f, z0 + 1.f, fx * fy * fz);
            }
        }

        const float delta = range * (1.0f / 64.0f);  // (t_far - t_near) / NUM_SAMPLES
        out[i * W + j] = valid ? sum * delta : 0.0f;
    }
}

extern "C" void kernel_launch(void* const* d_in, const int* in_sizes, int n_in,
                              void* d_out, int out_size, void* d_ws, size_t ws_size,
                              hipStream_t stream) {
    const float* vol  = (const float*)d_in[0];
    const float* wvt  = (const float*)d_in[1];
    const float* proj = (const float*)d_in[2];
    const float* cam  = (const float*)d_in[3];
    const float* bbox = (const float*)d_in[4];
    const int*   pH   = (const int*)d_in[5];
    const int*   pW   = (const int*)d_in[6];
    const int*   pmode= (const int*)d_in[7];
    float* out = (float*)d_out;

    int blocks = (out_size + 255) / 256;
    if (blocks < 1) blocks = 1;
    dsv_render<<<blocks, 256, 0, stream>>>(vol, wvt, proj, cam, bbox, pH, pW, pmode, out);
}